// Round 9
// baseline (168.289 us; speedup 1.0000x reference)
//
#include <hip/hip_runtime.h>

// PhysicsGuidedAttention: B=2, N=2048, D=768, H=12, Hd=64
// qkv = x @ w_qkv.T ; flash-attn with elevation bias ; out = attn_out @ w_proj.T + b_proj
// R9: attn = R8 structure + 64q/wave (two 32-q streams sharing K/V frag reads,
//     halving LDS-read per unit) + psum via ones-MFMA (VALU -> idle MFMA pipe,
//     no epilogue shfl/LDS). 128-thr blocks, grid (24,16,2) = 768 even, KV-split
//     combine as R8. GEMMs = 2-phase dbuf. cvt3 merges all converts.

typedef __attribute__((ext_vector_type(8))) short bf16x8;   // 8 bf16 = 4 VGPRs
typedef __attribute__((ext_vector_type(4))) float f32x4;
typedef __attribute__((ext_vector_type(16))) float f32x16;  // 32x32 accumulator

__device__ __forceinline__ unsigned short f2bf(float f) {
  unsigned int u = __builtin_bit_cast(unsigned int, f);
  u += 0x7fffu + ((u >> 16) & 1u);        // round-to-nearest-even
  return (unsigned short)(u >> 16);
}

__device__ __forceinline__ unsigned cvtpk(float lo, float hi) {
  unsigned r;
  asm("v_cvt_pk_bf16_f32 %0, %1, %2" : "=v"(r) : "v"(lo), "v"(hi));
  return r;
}

__device__ __forceinline__ float exp2v(float x) {
  float r;
  asm("v_exp_f32 %0, %1" : "=v"(r) : "v"(x));
  return r;
}

// XOR swizzle on element index: spreads 128B-stride row slots across banks.
__device__ __forceinline__ int sw8(int row) {
  return ((row ^ (row >> 3)) & 7) << 3;
}

__device__ __forceinline__ void gload16(const unsigned short* g, unsigned short* l) {
  __builtin_amdgcn_global_load_lds(
      (const __attribute__((address_space(1))) unsigned int*)g,
      (__attribute__((address_space(3))) unsigned int*)l, 16, 0, 0);
}

// ---------------------------------------------------------------------------
// f32 -> bf16 converts for x, w_qkv, w_proj in ONE launch.
__global__ __launch_bounds__(256)
void cvt3_kernel(const float* __restrict__ a, unsigned short* __restrict__ ao, int na8,
                 const float* __restrict__ b, unsigned short* __restrict__ bo, int nb8,
                 const float* __restrict__ c, unsigned short* __restrict__ co, int nc8) {
  int i = blockIdx.x * 256 + threadIdx.x;
  const float* src; unsigned short* dst;
  if (i < na8) { src = a; dst = ao; }
  else if ((i -= na8) < nb8) { src = b; dst = bo; }
  else if ((i -= nb8) < nc8) { src = c; dst = co; }
  else return;
  const float4 f0 = ((const float4*)src)[i * 2];
  const float4 f1 = ((const float4*)src)[i * 2 + 1];
  uint4 v;
  v.x = (unsigned)f2bf(f0.x) | ((unsigned)f2bf(f0.y) << 16);
  v.y = (unsigned)f2bf(f0.z) | ((unsigned)f2bf(f0.w) << 16);
  v.z = (unsigned)f2bf(f1.x) | ((unsigned)f2bf(f1.y) << 16);
  v.w = (unsigned)f2bf(f1.z) | ((unsigned)f2bf(f1.w) << 16);
  ((uint4*)dst)[i] = v;
}

// ---------------------------------------------------------------------------
// C[M,N] = A[M,K] @ B[N,K]^T, bf16, 128x128 tile, BK=32, 2-phase dbuf pipeline.
template<bool OUT_F32>
__global__ __launch_bounds__(256)
void gemm_bt_bf16(const unsigned short* __restrict__ Ap,
                  const unsigned short* __restrict__ Bp,
                  const float* __restrict__ bias, void* __restrict__ Cp,
                  int M, int N, int K) {
  __shared__ __align__(16) unsigned short lds_a[2][128 * 32];
  __shared__ __align__(16) unsigned short lds_b[2][128 * 32];
  const int t = threadIdx.x;
  const int l = t & 63;
  const int w = t >> 6;
  const int wr = w >> 1, wc = w & 1;
  const int brow = blockIdx.x * 128;
  const int bcol = blockIdx.y * 128;
  const int l15 = l & 15, l4 = l >> 4;

  const int srow = t >> 2;
  const int scol = (t & 3) * 8;
  const unsigned short* ga = Ap + (size_t)(brow + srow) * K + scol;
  const unsigned short* gb = Bp + (size_t)(bcol + srow) * K + scol;

  f32x4 acc[4][4] = {};
  const int nk = K >> 5;

  {
    unsigned short* la = lds_a[0] + w * 512;
    unsigned short* lb = lds_b[0] + w * 512;
    gload16(ga, la);
    gload16(ga + (size_t)64 * K, la + 2048);
    gload16(gb, lb);
    gload16(gb + (size_t)64 * K, lb + 2048);
  }
  __syncthreads();

  int buf = 0;
  for (int kt = 0; kt < nk; ++kt) {
    if (kt + 1 < nk) {
      const size_t ko = (size_t)(kt + 1) * 32;
      unsigned short* la = lds_a[buf ^ 1] + w * 512;
      unsigned short* lb = lds_b[buf ^ 1] + w * 512;
      gload16(ga + ko, la);
      gload16(ga + ko + (size_t)64 * K, la + 2048);
      gload16(gb + ko, lb);
      gload16(gb + ko + (size_t)64 * K, lb + 2048);
    }
    bf16x8 af[4], bfr[4];
#pragma unroll
    for (int i = 0; i < 4; ++i) {
      af[i]  = *(const bf16x8*)&lds_a[buf][(wr * 64 + i * 16 + l15) * 32 + l4 * 8];
      bfr[i] = *(const bf16x8*)&lds_b[buf][(wc * 64 + i * 16 + l15) * 32 + l4 * 8];
    }
#pragma unroll
    for (int i = 0; i < 4; ++i)
#pragma unroll
      for (int j = 0; j < 4; ++j)
        acc[i][j] = __builtin_amdgcn_mfma_f32_16x16x32_bf16(af[i], bfr[j], acc[i][j], 0, 0, 0);
    __syncthreads();
    buf ^= 1;
  }

#pragma unroll
  for (int i = 0; i < 4; ++i)
#pragma unroll
    for (int j = 0; j < 4; ++j)
#pragma unroll
      for (int r = 0; r < 4; ++r) {
        const int row = brow + wr * 64 + i * 16 + l4 * 4 + r;
        const int col = bcol + wc * 64 + j * 16 + l15;
        const float v = acc[i][j][r];
        if constexpr (OUT_F32) {
          ((float*)Cp)[(size_t)row * N + col] = v + bias[col];
        } else {
          ((unsigned short*)Cp)[(size_t)row * N + col] = f2bf(v);
        }
      }
}

// ---------------------------------------------------------------------------
// Flash attention, 32x32x16 MFMA, swapped QK^T, no max-tracking, KV-split x2.
// grid = (B*H, N/128, 2); 128 thr = 2 waves; wave w owns q rows
// [qA, qA+32) and [qB, qB+32) with qA = by*128 + w*64, qB = qA+32.
// The two q-streams share all K/V/ej LDS reads. psum accumulated on the MFMA
// pipe via an all-ones B operand (ps[r] has the same row mapping as o[nb][r]).
__global__ __launch_bounds__(128)
void attn_kernel(const unsigned short* __restrict__ qkv,
                 const float* __restrict__ elev,
                 const float* __restrict__ alpha_p,
                 float* __restrict__ O0, float* __restrict__ O1,
                 float* __restrict__ psums) {
  __shared__ __align__(16) unsigned short lds_k[2][64 * 64];   // [buf][kv][d] swz
  __shared__ __align__(16) unsigned short lds_vt[2][64 * 64];  // [buf][d][kv] swz
  __shared__ __align__(16) float lds_ej[2][64];

  const int t = threadIdx.x;
  const int l = t & 63;
  const int w = t >> 6;                    // 0..1
  const int l31 = l & 31;
  const int h = l >> 5;
  const int b = blockIdx.x / 12, hd = blockIdx.x % 12;
  const int qA = blockIdx.y * 128 + w * 64;
  const int qB = qA + 32;
  const int z = blockIdx.z;
  const int s_lo = z * 16, s_hi = s_lo + 16;

  const float cE = fmaxf(alpha_p[0], 0.f) * (1.4426950408889634f * 1e-3f);
  const float c1 = 0.18033688011112042f;   // 0.125 * log2(e)

  const size_t rs = 2304;
  const unsigned short* qbase = qkv + ((size_t)b * 2048) * rs + hd * 64;
  const unsigned short* kbase = qbase + 768;
  const unsigned short* vbase = qbase + 1536;

  bf16x8 qa0[4], qa1[4];
  {
    const unsigned short* qpA = qbase + (size_t)(qA + l31) * rs + h * 8;
    const unsigned short* qpB = qbase + (size_t)(qB + l31) * rs + h * 8;
#pragma unroll
    for (int ks = 0; ks < 4; ++ks) {
      qa0[ks] = *(const bf16x8*)(qpA + ks * 16);
      qa1[ks] = *(const bf16x8*)(qpB + ks * 16);
    }
  }
  const float eivA = elev[(size_t)b * 2048 + qA + l31] * cE;
  const float eivB = elev[(size_t)b * 2048 + qB + l31] * cE;

  // all-ones bf16 B operand for psum MFMA
  uint4 onesu; onesu.x = onesu.y = onesu.z = onesu.w = 0x3F803F80u;
  const bf16x8 onesf = __builtin_bit_cast(bf16x8, onesu);

  // staging (128 threads cover 64x64 K and V): R7/R8-proven patterns
  const int kr = t >> 1;          // 0..63
  const int kc = (t & 1) * 32;    // 4 x b128 at kc+8i
  const int vr = t >> 1;
  const int vh = (t & 1) * 32;

  uint4 rk[4], rv[4];
  float evn = 0.f;

  f32x16 oA[2] = {}, oB[2] = {};
  f32x16 psA = {}, psB = {};

  // ---- prologue: stage first tile of this half into buf 0 ----
  {
    const int kv0 = s_lo * 64;
#pragma unroll
    for (int i = 0; i < 4; ++i)
      rk[i] = *(const uint4*)(kbase + (size_t)(kv0 + kr) * rs + kc + 8 * i);
#pragma unroll
    for (int i = 0; i < 4; ++i)
      rv[i] = *(const uint4*)(vbase + (size_t)(kv0 + vr) * rs + vh + 8 * i);
    if (t < 64) evn = elev[(size_t)b * 2048 + kv0 + t];
#pragma unroll
    for (int i = 0; i < 4; ++i)
      *(uint4*)&lds_k[0][kr * 64 + ((kc + 8 * i) ^ sw8(kr))] = rk[i];
#pragma unroll
    for (int i = 0; i < 4; ++i) {
      union { uint4 u; unsigned short s[8]; } vu; vu.u = rv[i];
#pragma unroll
      for (int j = 0; j < 8; ++j) {
        const int d = vh + 8 * i + j;
        lds_vt[0][d * 64 + (vr ^ sw8(d))] = vu.s[j];
      }
    }
    if (t < 64) lds_ej[0][t] = evn * cE;
  }
  __syncthreads();

  for (int it = s_lo; it < s_hi; ++it) {
    const int cur = it & 1;                // s_lo even -> starts at buf 0
    const bool more = it + 1 < s_hi;
    if (more) {                            // prefetch next tile into registers
      const int kvn = (it + 1) * 64;
#pragma unroll
      for (int i = 0; i < 4; ++i)
        rk[i] = *(const uint4*)(kbase + (size_t)(kvn + kr) * rs + kc + 8 * i);
#pragma unroll
      for (int i = 0; i < 4; ++i)
        rv[i] = *(const uint4*)(vbase + (size_t)(kvn + vr) * rs + vh + 8 * i);
      if (t < 64) evn = elev[(size_t)b * 2048 + kvn + t];
    }

    // --- S^T = K x Q, both q-streams share each K fragment ---
    f32x16 stA[2] = {}, stB[2] = {};
    __builtin_amdgcn_s_setprio(1);
#pragma unroll
    for (int kst = 0; kst < 4; ++kst) {
      const int col = kst * 16 + h * 8;
#pragma unroll
      for (int mb = 0; mb < 2; ++mb) {
        const int row = mb * 32 + l31;
        bf16x8 kf = *(const bf16x8*)&lds_k[cur][row * 64 + (col ^ sw8(row))];
        stA[mb] = __builtin_amdgcn_mfma_f32_32x32x16_bf16(kf, qa0[kst], stA[mb], 0, 0, 0);
        stB[mb] = __builtin_amdgcn_mfma_f32_32x32x16_bf16(kf, qa1[kst], stB[mb], 0, 0, 0);
      }
    }
    __builtin_amdgcn_s_setprio(0);

    // --- softmax both streams (shared ej reads) + in-register P pack ---
    bf16x8 paA[4], paB[4];
#pragma unroll
    for (int mb = 0; mb < 2; ++mb) {
      float pA16[16], pB16[16];
#pragma unroll
      for (int rr = 0; rr < 4; ++rr) {
        const float4 ejq = *(const float4*)&lds_ej[cur][mb * 32 + rr * 8 + h * 4];
#pragma unroll
        for (int jl = 0; jl < 4; ++jl) {
          const int r = rr * 4 + jl;
          const float bmA = __builtin_amdgcn_fmed3f(ejq[jl] - eivA, 0.f, 14.4269504f);
          const float bmB = __builtin_amdgcn_fmed3f(ejq[jl] - eivB, 0.f, 14.4269504f);
          pA16[r] = exp2v(__builtin_fmaf(stA[mb][r], c1, -bmA));
          pB16[r] = exp2v(__builtin_fmaf(stB[mb][r], c1, -bmB));
        }
      }
#pragma unroll
      for (int ks2 = 0; ks2 < 2; ++ks2) {
        {
          unsigned u0 = cvtpk(pA16[ks2 * 8 + 0], pA16[ks2 * 8 + 1]);
          unsigned u1 = cvtpk(pA16[ks2 * 8 + 2], pA16[ks2 * 8 + 3]);
          unsigned v0 = cvtpk(pA16[ks2 * 8 + 4], pA16[ks2 * 8 + 5]);
          unsigned v1 = cvtpk(pA16[ks2 * 8 + 6], pA16[ks2 * 8 + 7]);
          asm volatile("v_permlane32_swap_b32 %0, %1" : "+v"(u0), "+v"(v0));
          asm volatile("v_permlane32_swap_b32 %0, %1" : "+v"(u1), "+v"(v1));
          uint4 fr; fr.x = u0; fr.y = u1; fr.z = v0; fr.w = v1;
          paA[mb * 2 + ks2] = __builtin_bit_cast(bf16x8, fr);
        }
        {
          unsigned u0 = cvtpk(pB16[ks2 * 8 + 0], pB16[ks2 * 8 + 1]);
          unsigned u1 = cvtpk(pB16[ks2 * 8 + 2], pB16[ks2 * 8 + 3]);
          unsigned v0 = cvtpk(pB16[ks2 * 8 + 4], pB16[ks2 * 8 + 5]);
          unsigned v1 = cvtpk(pB16[ks2 * 8 + 6], pB16[ks2 * 8 + 7]);
          asm volatile("v_permlane32_swap_b32 %0, %1" : "+v"(u0), "+v"(v0));
          asm volatile("v_permlane32_swap_b32 %0, %1" : "+v"(u1), "+v"(v1));
          uint4 fr; fr.x = u0; fr.y = u1; fr.z = v0; fr.w = v1;
          paB[mb * 2 + ks2] = __builtin_bit_cast(bf16x8, fr);
        }
      }
    }

    // --- O += P @ V (shared V frags) + psum via ones-MFMA ---
    __builtin_amdgcn_s_setprio(1);
#pragma unroll
    for (int ks = 0; ks < 4; ++ks) {
      const int col = ks * 16 + h * 8;
#pragma unroll
      for (int nb = 0; nb < 2; ++nb) {
        const int row = nb * 32 + l31;
        bf16x8 vf = *(const bf16x8*)&lds_vt[cur][row * 64 + (col ^ sw8(row))];
        oA[nb] = __builtin_amdgcn_mfma_f32_32x32x16_bf16(paA[ks], vf, oA[nb], 0, 0, 0);
        oB[nb] = __builtin_amdgcn_mfma_f32_32x32x16_bf16(paB[ks], vf, oB[nb], 0, 0, 0);
      }
      psA = __builtin_amdgcn_mfma_f32_32x32x16_bf16(paA[ks], onesf, psA, 0, 0, 0);
      psB = __builtin_amdgcn_mfma_f32_32x32x16_bf16(paB[ks], onesf, psB, 0, 0, 0);
    }
    __builtin_amdgcn_s_setprio(0);

    // --- T14 late-write next tile ---
    if (more) {
      const int nxt = cur ^ 1;
#pragma unroll
      for (int i = 0; i < 4; ++i)
        *(uint4*)&lds_k[nxt][kr * 64 + ((kc + 8 * i) ^ sw8(kr))] = rk[i];
#pragma unroll
      for (int i = 0; i < 4; ++i) {
        union { uint4 u; unsigned short s[8]; } vu; vu.u = rv[i];
#pragma unroll
        for (int j = 0; j < 8; ++j) {
          const int d = vh + 8 * i + j;
          lds_vt[nxt][d * 64 + (vr ^ sw8(d))] = vu.s[j];
        }
      }
      if (t < 64) lds_ej[nxt][t] = evn * cE;
      __syncthreads();
    }
  }

  // --- partial epilogue: psums from ps regs (row mapping = o rows) ---
  const int pbase = z * (24 * 2048) + blockIdx.x * 2048;
  if (l31 == 0) {
#pragma unroll
    for (int r = 0; r < 16; ++r) {
      const int qr = (r & 3) + 8 * (r >> 2) + 4 * h;
      psums[pbase + qA + qr] = psA[r];
      psums[pbase + qB + qr] = psB[r];
    }
  }
  float* OD = z ? O1 : O0;
#pragma unroll
  for (int nb = 0; nb < 2; ++nb) {
    const int col = hd * 64 + nb * 32 + l31;
#pragma unroll
    for (int rr = 0; rr < 4; ++rr)
#pragma unroll
      for (int jl = 0; jl < 4; ++jl) {
        const int qr = rr * 8 + h * 4 + jl;
        OD[((size_t)b * 2048 + qA + qr) * 768 + col] = oA[nb][rr * 4 + jl];
        OD[((size_t)b * 2048 + qB + qr) * 768 + col] = oB[nb][rr * 4 + jl];
      }
  }
}

// ---------------------------------------------------------------------------
// Combine the two KV-halves: aob = bf16((O0+O1) / (l0+l1)). grid 4096 x 192.
__global__ __launch_bounds__(192)
void combine_kernel(const float* __restrict__ O0, const float* __restrict__ O1,
                    const float* __restrict__ psums, unsigned short* __restrict__ aob) {
  const int row = blockIdx.x;              // 0..4095 = b*2048+q
  const int b = row >> 11, q = row & 2047;
  const int c = threadIdx.x * 4;
  const int hd = c >> 6;
  const int pidx = (b * 12 + hd) * 2048 + q;
  const float inv = 1.0f / (psums[pidx] + psums[24 * 2048 + pidx]);
  const size_t off = (size_t)row * 768 + c;
  const float4 a = *(const float4*)&O0[off];
  const float4 d = *(const float4*)&O1[off];
  ushort4 r;
  r.x = f2bf((a.x + d.x) * inv);
  r.y = f2bf((a.y + d.y) * inv);
  r.z = f2bf((a.z + d.z) * inv);
  r.w = f2bf((a.w + d.w) * inv);
  *(ushort4*)&aob[off] = r;
}

extern "C" void kernel_launch(void* const* d_in, const int* in_sizes, int n_in,
                              void* d_out, int out_size, void* d_ws, size_t ws_size,
                              hipStream_t stream) {
  const float* x      = (const float*)d_in[0];   // [2,2048,768]
  const float* elev   = (const float*)d_in[1];   // [2,2048]
  const float* w_qkv  = (const float*)d_in[2];   // [2304,768]
  const float* w_proj = (const float*)d_in[3];   // [768,768]
  const float* b_proj = (const float*)d_in[4];   // [768]
  const float* alpha  = (const float*)d_in[5];   // [1]
  float* out = (float*)d_out;                    // [2,2048,768] f32

  // ws layout:
  //   qkvb  : bf16 [4096,2304]                           (18.9 MB)
  //   xb    : bf16 [4096,768]  -> reused as aob          ( 6.3 MB)
  //   wqkvb : bf16 [2304,768]                            ( 3.5 MB)
  //   wprojb: bf16 [768,768]                             ( 1.2 MB)
  //   P0    : f32  [4096,768]  attn half-0 partial       (12.6 MB)
  //   psums : f32  [2][24*2048]                          ( 0.4 MB)
  // attn half-1 partial lives in d_out (f32, dead until gemm2).
  unsigned short* qkvb   = (unsigned short*)d_ws;
  unsigned short* xb     = qkvb + (size_t)4096 * 2304;
  unsigned short* aob    = xb;
  unsigned short* wqkvb  = xb + (size_t)4096 * 768;
  unsigned short* wprojb = wqkvb + (size_t)2304 * 768;
  float* P0    = (float*)(wprojb + (size_t)768 * 768);
  float* psums = P0 + (size_t)4096 * 768;

  cvt3_kernel<<<2688, 256, 0, stream>>>(x, xb, 4096 * 768 / 8,
                                        w_qkv, wqkvb, 2304 * 768 / 8,
                                        w_proj, wprojb, 768 * 768 / 8);

  gemm_bt_bf16<false><<<dim3(32, 18), 256, 0, stream>>>(
      xb, wqkvb, nullptr, qkvb, 4096, 2304, 768);

  attn_kernel<<<dim3(24, 16, 2), 128, 0, stream>>>(qkvb, elev, alpha,
                                                   P0, out, psums);

  combine_kernel<<<4096, 192, 0, stream>>>(P0, out, psums, aob);

  gemm_bt_bf16<true><<<dim3(32, 6), 256, 0, stream>>>(
      aob, wprojb, b_proj, out, 4096, 768, 768);
}

// Round 10
// 117.745 us; speedup vs baseline: 1.4293x; 1.4293x over previous
//
#include <hip/hip_runtime.h>

// PhysicsGuidedAttention: B=2, N=2048, D=768, H=12, Hd=64
// qkv = x @ w_qkv.T ; flash-attn with elevation bias ; out = attn_out @ w_proj.T + b_proj
// R10: attn = R3's measured-best kernel (384 blocks, 4-wave, dbuf, 1 barrier/iter)
//      + ones-MFMA psum (R9-validated) -> per-lane normalize, no epilogue LDS/shfl.
//      No z-split/combine (measured neutral). gemm1 fuses x f32->bf16 into A-staging.
//      gemm2 on 64-row tiles (384 blocks). cvt only for the two weight matrices.

typedef __attribute__((ext_vector_type(8))) short bf16x8;   // 8 bf16 = 4 VGPRs
typedef __attribute__((ext_vector_type(4))) float f32x4;
typedef __attribute__((ext_vector_type(16))) float f32x16;  // 32x32 accumulator

__device__ __forceinline__ unsigned short f2bf(float f) {
  unsigned int u = __builtin_bit_cast(unsigned int, f);
  u += 0x7fffu + ((u >> 16) & 1u);        // round-to-nearest-even
  return (unsigned short)(u >> 16);
}

__device__ __forceinline__ unsigned cvtpk(float lo, float hi) {
  unsigned r;
  asm("v_cvt_pk_bf16_f32 %0, %1, %2" : "=v"(r) : "v"(lo), "v"(hi));
  return r;
}

__device__ __forceinline__ float exp2v(float x) {
  float r;
  asm("v_exp_f32 %0, %1" : "=v"(r) : "v"(x));
  return r;
}

// XOR swizzle on element index: spreads 128B-stride row slots across banks.
__device__ __forceinline__ int sw8(int row) {
  return ((row ^ (row >> 3)) & 7) << 3;
}

__device__ __forceinline__ void gload16(const unsigned short* g, unsigned short* l) {
  __builtin_amdgcn_global_load_lds(
      (const __attribute__((address_space(1))) unsigned int*)g,
      (__attribute__((address_space(3))) unsigned int*)l, 16, 0, 0);
}

// ---------------------------------------------------------------------------
// f32 -> bf16 converts for w_qkv and w_proj in one launch.
__global__ __launch_bounds__(256)
void cvt2_kernel(const float* __restrict__ a, unsigned short* __restrict__ ao, int na8,
                 const float* __restrict__ b, unsigned short* __restrict__ bo, int nb8) {
  int i = blockIdx.x * 256 + threadIdx.x;
  const float* src; unsigned short* dst;
  if (i < na8) { src = a; dst = ao; }
  else {
    i -= na8;
    if (i >= nb8) return;
    src = b; dst = bo;
  }
  const float4 f0 = ((const float4*)src)[i * 2];
  const float4 f1 = ((const float4*)src)[i * 2 + 1];
  uint4 v;
  v.x = cvtpk(f0.x, f0.y);
  v.y = cvtpk(f0.z, f0.w);
  v.z = cvtpk(f1.x, f1.y);
  v.w = cvtpk(f1.z, f1.w);
  ((uint4*)dst)[i] = v;
}

// ---------------------------------------------------------------------------
// gemm1: C[M,N] = A[M,K] @ B[N,K]^T with A = f32 (converted in staging regs),
// B bf16 via gload_lds, C bf16. 128x128 tile, BK=32, 2-phase dbuf (T14 for A).
__global__ __launch_bounds__(256)
void gemm_a32_kernel(const float* __restrict__ Ap,
                     const unsigned short* __restrict__ Bp,
                     unsigned short* __restrict__ Cp, int M, int N, int K) {
  __shared__ __align__(16) unsigned short lds_a[2][128 * 32];
  __shared__ __align__(16) unsigned short lds_b[2][128 * 32];
  const int t = threadIdx.x;
  const int l = t & 63;
  const int w = t >> 6;
  const int wr = w >> 1, wc = w & 1;
  const int brow = blockIdx.x * 128;
  const int bcol = blockIdx.y * 128;
  const int l15 = l & 15, l4 = l >> 4;

  const int srow = t >> 2;
  const int scol = (t & 3) * 8;
  const float* ga = Ap + (size_t)(brow + srow) * K + scol;
  const unsigned short* gb = Bp + (size_t)(bcol + srow) * K + scol;

  f32x4 acc[4][4] = {};
  const int nk = K >> 5;

  float4 fa[4];
  // prologue: tile 0
  {
    fa[0] = *(const float4*)ga;
    fa[1] = *(const float4*)(ga + 4);
    fa[2] = *(const float4*)(ga + (size_t)64 * K);
    fa[3] = *(const float4*)(ga + (size_t)64 * K + 4);
    unsigned short* lb = lds_b[0] + w * 512;
    gload16(gb, lb);
    gload16(gb + (size_t)64 * K, lb + 2048);
    uint4 u0, u1;
    u0.x = cvtpk(fa[0].x, fa[0].y); u0.y = cvtpk(fa[0].z, fa[0].w);
    u0.z = cvtpk(fa[1].x, fa[1].y); u0.w = cvtpk(fa[1].z, fa[1].w);
    u1.x = cvtpk(fa[2].x, fa[2].y); u1.y = cvtpk(fa[2].z, fa[2].w);
    u1.z = cvtpk(fa[3].x, fa[3].y); u1.w = cvtpk(fa[3].z, fa[3].w);
    *(uint4*)&lds_a[0][srow * 32 + scol] = u0;
    *(uint4*)&lds_a[0][(srow + 64) * 32 + scol] = u1;
  }
  __syncthreads();

  int buf = 0;
  for (int kt = 0; kt < nk; ++kt) {
    const bool more = kt + 1 < nk;
    if (more) {                            // issue next-tile loads early
      const size_t ko = (size_t)(kt + 1) * 32;
      fa[0] = *(const float4*)(ga + ko);
      fa[1] = *(const float4*)(ga + ko + 4);
      fa[2] = *(const float4*)(ga + ko + (size_t)64 * K);
      fa[3] = *(const float4*)(ga + ko + (size_t)64 * K + 4);
      unsigned short* lb = lds_b[buf ^ 1] + w * 512;
      gload16(gb + ko, lb);
      gload16(gb + ko + (size_t)64 * K, lb + 2048);
    }
    bf16x8 af[4], bfr[4];
#pragma unroll
    for (int i = 0; i < 4; ++i) {
      af[i]  = *(const bf16x8*)&lds_a[buf][(wr * 64 + i * 16 + l15) * 32 + l4 * 8];
      bfr[i] = *(const bf16x8*)&lds_b[buf][(wc * 64 + i * 16 + l15) * 32 + l4 * 8];
    }
#pragma unroll
    for (int i = 0; i < 4; ++i)
#pragma unroll
      for (int j = 0; j < 4; ++j)
        acc[i][j] = __builtin_amdgcn_mfma_f32_16x16x32_bf16(af[i], bfr[j], acc[i][j], 0, 0, 0);
    if (more) {                            // T14 late-write A (hidden under MFMA)
      uint4 u0, u1;
      u0.x = cvtpk(fa[0].x, fa[0].y); u0.y = cvtpk(fa[0].z, fa[0].w);
      u0.z = cvtpk(fa[1].x, fa[1].y); u0.w = cvtpk(fa[1].z, fa[1].w);
      u1.x = cvtpk(fa[2].x, fa[2].y); u1.y = cvtpk(fa[2].z, fa[2].w);
      u1.z = cvtpk(fa[3].x, fa[3].y); u1.w = cvtpk(fa[3].z, fa[3].w);
      *(uint4*)&lds_a[buf ^ 1][srow * 32 + scol] = u0;
      *(uint4*)&lds_a[buf ^ 1][(srow + 64) * 32 + scol] = u1;
    }
    __syncthreads();
    buf ^= 1;
  }

#pragma unroll
  for (int i = 0; i < 4; ++i)
#pragma unroll
    for (int j = 0; j < 4; ++j)
#pragma unroll
      for (int r = 0; r < 4; ++r) {
        const int row = brow + wr * 64 + i * 16 + l4 * 4 + r;
        const int col = bcol + wc * 64 + j * 16 + l15;
        Cp[(size_t)row * N + col] = f2bf(acc[i][j][r]);
      }
}

// ---------------------------------------------------------------------------
// gemm2: C[M,N] = A[M,K] @ B[N,K]^T + bias, all-bf16 inputs via gload_lds,
// C f32. 64x128 tile (384 blocks at M=4096,N=768), BK=32, 2-phase dbuf.
__global__ __launch_bounds__(256)
void gemm2_kernel(const unsigned short* __restrict__ Ap,
                  const unsigned short* __restrict__ Bp,
                  const float* __restrict__ bias, float* __restrict__ Cp,
                  int M, int N, int K) {
  __shared__ __align__(16) unsigned short lds_a[2][64 * 32];
  __shared__ __align__(16) unsigned short lds_b[2][128 * 32];
  const int t = threadIdx.x;
  const int l = t & 63;
  const int w = t >> 6;
  const int wr = w >> 1, wc = w & 1;          // wave: rows wr*32, cols wc*64
  const int brow = blockIdx.x * 64;
  const int bcol = blockIdx.y * 128;
  const int l15 = l & 15, l4 = l >> 4;

  const int srow = t >> 2;
  const int scol = (t & 3) * 8;
  const unsigned short* ga = Ap + (size_t)(brow + srow) * K + scol;
  const unsigned short* gb = Bp + (size_t)(bcol + srow) * K + scol;

  f32x4 acc[2][4] = {};
  const int nk = K >> 5;

  {
    gload16(ga, lds_a[0] + w * 512);
    unsigned short* lb = lds_b[0] + w * 512;
    gload16(gb, lb);
    gload16(gb + (size_t)64 * K, lb + 2048);
  }
  __syncthreads();

  int buf = 0;
  for (int kt = 0; kt < nk; ++kt) {
    if (kt + 1 < nk) {
      const size_t ko = (size_t)(kt + 1) * 32;
      gload16(ga + ko, lds_a[buf ^ 1] + w * 512);
      unsigned short* lb = lds_b[buf ^ 1] + w * 512;
      gload16(gb + ko, lb);
      gload16(gb + ko + (size_t)64 * K, lb + 2048);
    }
    bf16x8 af[2], bfr[4];
#pragma unroll
    for (int i = 0; i < 2; ++i)
      af[i] = *(const bf16x8*)&lds_a[buf][(wr * 32 + i * 16 + l15) * 32 + l4 * 8];
#pragma unroll
    for (int j = 0; j < 4; ++j)
      bfr[j] = *(const bf16x8*)&lds_b[buf][(wc * 64 + j * 16 + l15) * 32 + l4 * 8];
#pragma unroll
    for (int i = 0; i < 2; ++i)
#pragma unroll
      for (int j = 0; j < 4; ++j)
        acc[i][j] = __builtin_amdgcn_mfma_f32_16x16x32_bf16(af[i], bfr[j], acc[i][j], 0, 0, 0);
    __syncthreads();
    buf ^= 1;
  }

#pragma unroll
  for (int i = 0; i < 2; ++i)
#pragma unroll
    for (int j = 0; j < 4; ++j)
#pragma unroll
      for (int r = 0; r < 4; ++r) {
        const int row = brow + wr * 32 + i * 16 + l4 * 4 + r;
        const int col = bcol + wc * 64 + j * 16 + l15;
        Cp[(size_t)row * N + col] = acc[i][j][r] + bias[col];
      }
}

// ---------------------------------------------------------------------------
// Flash attention (R3 structure), 32x32x16 MFMA, swapped QK^T, no max-tracking,
// psum via ones-MFMA -> purely per-lane normalization (no epilogue LDS/shfl).
// grid = (B*H, N/128); 256 thr = 4 waves; wave w owns q [q0, q0+32).
__global__ __launch_bounds__(256)
void attn_kernel(const unsigned short* __restrict__ qkv,
                 const float* __restrict__ elev,
                 const float* __restrict__ alpha_p,
                 unsigned short* __restrict__ aout) {
  __shared__ __align__(16) unsigned short lds_k[2][64 * 64];
  __shared__ __align__(16) unsigned short lds_vt[2][64 * 64];   // [d][kv], swizzled
  __shared__ __align__(16) float lds_ej[2][64];

  const int t = threadIdx.x;
  const int l = t & 63;
  const int w = t >> 6;
  const int l31 = l & 31;
  const int h = l >> 5;
  const int b = blockIdx.x / 12, hd = blockIdx.x % 12;
  const int q0 = blockIdx.y * 128 + w * 32;

  const float cE = fmaxf(alpha_p[0], 0.f) * (1.4426950408889634f * 1e-3f);
  const float c1 = 0.18033688011112042f;   // 0.125 * log2(e)

  const size_t rs = 2304;
  const unsigned short* qbase = qkv + ((size_t)b * 2048) * rs + hd * 64;
  const unsigned short* kbase = qbase + 768;
  const unsigned short* vbase = qbase + 1536;

  bf16x8 qa[4];
  {
    const unsigned short* qp = qbase + (size_t)(q0 + l31) * rs + h * 8;
#pragma unroll
    for (int ks = 0; ks < 4; ++ks) qa[ks] = *(const bf16x8*)(qp + ks * 16);
  }
  const float eiv = elev[(size_t)b * 2048 + q0 + l31] * cE;

  // all-ones bf16 B operand for psum MFMA
  uint4 onesu; onesu.x = onesu.y = onesu.z = onesu.w = 0x3F803F80u;
  const bf16x8 onesf = __builtin_bit_cast(bf16x8, onesu);

  f32x16 o[2] = {};
  f32x16 ps = {};

  const int sr = t >> 3;          // staging row 0..31
  const int sc = (t & 7) * 8;     // staging col

  uint4 rk[2], rv[2];
  float evn = 0.f;

  // prologue: stage tile 0
#pragma unroll
  for (int p = 0; p < 2; ++p) {
    const int r = p * 32 + sr;
    rk[p] = *(const uint4*)(kbase + (size_t)r * rs + sc);
    rv[p] = *(const uint4*)(vbase + (size_t)r * rs + sc);
  }
  if (t < 64) evn = elev[(size_t)b * 2048 + t];
#pragma unroll
  for (int p = 0; p < 2; ++p) {
    const int r = p * 32 + sr;
    *(uint4*)&lds_k[0][r * 64 + (sc ^ sw8(r))] = rk[p];
    union { uint4 u; unsigned short s[8]; } vu; vu.u = rv[p];
#pragma unroll
    for (int j = 0; j < 8; ++j) {
      const int d = sc + j;
      lds_vt[0][d * 64 + (r ^ sw8(d))] = vu.s[j];
    }
  }
  if (t < 64) lds_ej[0][t] = evn * cE;
  __syncthreads();

  for (int it = 0; it < 32; ++it) {
    const int cur = it & 1;
    const bool more = it < 31;
    if (more) {
      const int kv1 = (it + 1) * 64;
#pragma unroll
      for (int p = 0; p < 2; ++p) {
        const int r = kv1 + p * 32 + sr;
        rk[p] = *(const uint4*)(kbase + (size_t)r * rs + sc);
        rv[p] = *(const uint4*)(vbase + (size_t)r * rs + sc);
      }
      if (t < 64) evn = elev[(size_t)b * 2048 + kv1 + t];
    }

    // --- S^T = K x Q ---
    f32x16 st[2] = {};
    __builtin_amdgcn_s_setprio(1);
#pragma unroll
    for (int kst = 0; kst < 4; ++kst) {
      const int col = kst * 16 + h * 8;
#pragma unroll
      for (int mb = 0; mb < 2; ++mb) {
        const int row = mb * 32 + l31;
        bf16x8 kf = *(const bf16x8*)&lds_k[cur][row * 64 + (col ^ sw8(row))];
        st[mb] = __builtin_amdgcn_mfma_f32_32x32x16_bf16(kf, qa[kst], st[mb], 0, 0, 0);
      }
    }
    __builtin_amdgcn_s_setprio(0);

    // --- softmax (no max-tracking) + in-register P pack ---
    bf16x8 pa[4];
#pragma unroll
    for (int mb = 0; mb < 2; ++mb) {
      float p16[16];
#pragma unroll
      for (int rr = 0; rr < 4; ++rr) {
        const float4 ejq = *(const float4*)&lds_ej[cur][mb * 32 + rr * 8 + h * 4];
#pragma unroll
        for (int jl = 0; jl < 4; ++jl) {
          const int r = rr * 4 + jl;
          const float bm = __builtin_amdgcn_fmed3f(ejq[jl] - eiv, 0.f, 14.4269504f);
          p16[r] = exp2v(__builtin_fmaf(st[mb][r], c1, -bm));
        }
      }
#pragma unroll
      for (int ks2 = 0; ks2 < 2; ++ks2) {
        unsigned u0 = cvtpk(p16[ks2 * 8 + 0], p16[ks2 * 8 + 1]);
        unsigned u1 = cvtpk(p16[ks2 * 8 + 2], p16[ks2 * 8 + 3]);
        unsigned v0 = cvtpk(p16[ks2 * 8 + 4], p16[ks2 * 8 + 5]);
        unsigned v1 = cvtpk(p16[ks2 * 8 + 6], p16[ks2 * 8 + 7]);
        asm volatile("v_permlane32_swap_b32 %0, %1" : "+v"(u0), "+v"(v0));
        asm volatile("v_permlane32_swap_b32 %0, %1" : "+v"(u1), "+v"(v1));
        uint4 fr; fr.x = u0; fr.y = u1; fr.z = v0; fr.w = v1;
        pa[mb * 2 + ks2] = __builtin_bit_cast(bf16x8, fr);
      }
    }

    // --- O += P @ V ; psum via ones-MFMA (same row mapping as O) ---
    __builtin_amdgcn_s_setprio(1);
#pragma unroll
    for (int ks = 0; ks < 4; ++ks) {
      const int col = ks * 16 + h * 8;
#pragma unroll
      for (int nb = 0; nb < 2; ++nb) {
        const int row = nb * 32 + l31;
        bf16x8 vf = *(const bf16x8*)&lds_vt[cur][row * 64 + (col ^ sw8(row))];
        o[nb] = __builtin_amdgcn_mfma_f32_32x32x16_bf16(pa[ks], vf, o[nb], 0, 0, 0);
      }
      ps = __builtin_amdgcn_mfma_f32_32x32x16_bf16(pa[ks], onesf, ps, 0, 0, 0);
    }
    __builtin_amdgcn_s_setprio(0);

    // --- write next tile ---
    if (more) {
      const int nxt = cur ^ 1;
#pragma unroll
      for (int p = 0; p < 2; ++p) {
        const int r = p * 32 + sr;
        *(uint4*)&lds_k[nxt][r * 64 + (sc ^ sw8(r))] = rk[p];
        union { uint4 u; unsigned short s[8]; } vu; vu.u = rv[p];
#pragma unroll
        for (int j = 0; j < 8; ++j) {
          const int d = sc + j;
          lds_vt[nxt][d * 64 + (r ^ sw8(d))] = vu.s[j];
        }
      }
      if (t < 64) lds_ej[nxt][t] = evn * cE;
      __syncthreads();
    }
  }

  // --- epilogue: purely per-lane normalize (ps rows == o rows), store bf16 ---
  float inv[16];
#pragma unroll
  for (int r = 0; r < 16; ++r) inv[r] = 1.0f / ps[r];
#pragma unroll
  for (int nb = 0; nb < 2; ++nb) {
    const int col = hd * 64 + nb * 32 + l31;
#pragma unroll
    for (int rr = 0; rr < 4; ++rr)
#pragma unroll
      for (int jl = 0; jl < 4; ++jl) {
        const int r = rr * 4 + jl;
        const int q = q0 + rr * 8 + h * 4 + jl;
        aout[((size_t)b * 2048 + q) * 768 + col] = f2bf(o[nb][r] * inv[r]);
      }
  }
}

extern "C" void kernel_launch(void* const* d_in, const int* in_sizes, int n_in,
                              void* d_out, int out_size, void* d_ws, size_t ws_size,
                              hipStream_t stream) {
  const float* x      = (const float*)d_in[0];   // [2,2048,768]
  const float* elev   = (const float*)d_in[1];   // [2,2048]
  const float* w_qkv  = (const float*)d_in[2];   // [2304,768]
  const float* w_proj = (const float*)d_in[3];   // [768,768]
  const float* b_proj = (const float*)d_in[4];   // [768]
  const float* alpha  = (const float*)d_in[5];   // [1]
  float* out = (float*)d_out;                    // [2,2048,768] f32

  // ws layout (bf16): qkvb [4096,2304] ; aob [4096,768] ; wqkvb [2304,768] ;
  // wprojb [768,768]  => 29.9 MB total
  unsigned short* qkvb   = (unsigned short*)d_ws;
  unsigned short* aob    = qkvb + (size_t)4096 * 2304;
  unsigned short* wqkvb  = aob + (size_t)4096 * 768;
  unsigned short* wprojb = wqkvb + (size_t)2304 * 768;

  // convert the two weight matrices (x is converted inside gemm1 staging)
  cvt2_kernel<<<1152, 256, 0, stream>>>(w_qkv, wqkvb, 2304 * 768 / 8,
                                        w_proj, wprojb, 768 * 768 / 8);

  // 1) qkv = x @ w_qkv^T   (A = f32 x, converted in-register)
  gemm_a32_kernel<<<dim3(32, 18), 256, 0, stream>>>(
      x, wqkvb, qkvb, 4096, 2304, 768);

  // 2) flash attention with elevation bias -> normalized bf16 aob
  attn_kernel<<<dim3(24, 16), 256, 0, stream>>>(qkvb, elev, alpha, aob);

  // 3) out = aob @ w_proj^T + b_proj
  gemm2_kernel<<<dim3(64, 6), 256, 0, stream>>>(
      aob, wprojb, b_proj, out, 4096, 768, 768);
}

// Round 11
// 100.459 us; speedup vs baseline: 1.6752x; 1.1721x over previous
//
#include <hip/hip_runtime.h>

// PhysicsGuidedAttention: B=2, N=2048, D=768, H=12, Hd=64
// qkv = x @ w_qkv.T ; flash-attn with elevation bias ; out = attn_out @ w_proj.T + b_proj
// R11: attn = R10's proven per-wave loop, restructured to 8-wave/512-thread
//      blocks with 256 q each, grid (24,8)=192 blocks: staging amortized 2x,
//      2 waves/SIMD latency hiding, same-(b,h) blocks share one XCD's L2.
//      gemm1 fuses x f32->bf16 in staging; gemm2 64-row tiles; cvt2 weights only.

typedef __attribute__((ext_vector_type(8))) short bf16x8;   // 8 bf16 = 4 VGPRs
typedef __attribute__((ext_vector_type(4))) float f32x4;
typedef __attribute__((ext_vector_type(16))) float f32x16;  // 32x32 accumulator

__device__ __forceinline__ unsigned short f2bf(float f) {
  unsigned int u = __builtin_bit_cast(unsigned int, f);
  u += 0x7fffu + ((u >> 16) & 1u);        // round-to-nearest-even
  return (unsigned short)(u >> 16);
}

__device__ __forceinline__ unsigned cvtpk(float lo, float hi) {
  unsigned r;
  asm("v_cvt_pk_bf16_f32 %0, %1, %2" : "=v"(r) : "v"(lo), "v"(hi));
  return r;
}

__device__ __forceinline__ float exp2v(float x) {
  float r;
  asm("v_exp_f32 %0, %1" : "=v"(r) : "v"(x));
  return r;
}

// XOR swizzle on element index: spreads 128B-stride row slots across banks.
__device__ __forceinline__ int sw8(int row) {
  return ((row ^ (row >> 3)) & 7) << 3;
}

__device__ __forceinline__ void gload16(const unsigned short* g, unsigned short* l) {
  __builtin_amdgcn_global_load_lds(
      (const __attribute__((address_space(1))) unsigned int*)g,
      (__attribute__((address_space(3))) unsigned int*)l, 16, 0, 0);
}

// ---------------------------------------------------------------------------
// f32 -> bf16 converts for w_qkv and w_proj in one launch.
__global__ __launch_bounds__(256)
void cvt2_kernel(const float* __restrict__ a, unsigned short* __restrict__ ao, int na8,
                 const float* __restrict__ b, unsigned short* __restrict__ bo, int nb8) {
  int i = blockIdx.x * 256 + threadIdx.x;
  const float* src; unsigned short* dst;
  if (i < na8) { src = a; dst = ao; }
  else {
    i -= na8;
    if (i >= nb8) return;
    src = b; dst = bo;
  }
  const float4 f0 = ((const float4*)src)[i * 2];
  const float4 f1 = ((const float4*)src)[i * 2 + 1];
  uint4 v;
  v.x = cvtpk(f0.x, f0.y);
  v.y = cvtpk(f0.z, f0.w);
  v.z = cvtpk(f1.x, f1.y);
  v.w = cvtpk(f1.z, f1.w);
  ((uint4*)dst)[i] = v;
}

// ---------------------------------------------------------------------------
// gemm1: C[M,N] = A[M,K] @ B[N,K]^T with A = f32 (converted in staging regs),
// B bf16 via gload_lds, C bf16. 128x128 tile, BK=32, 2-phase dbuf (T14 for A).
__global__ __launch_bounds__(256)
void gemm_a32_kernel(const float* __restrict__ Ap,
                     const unsigned short* __restrict__ Bp,
                     unsigned short* __restrict__ Cp, int M, int N, int K) {
  __shared__ __align__(16) unsigned short lds_a[2][128 * 32];
  __shared__ __align__(16) unsigned short lds_b[2][128 * 32];
  const int t = threadIdx.x;
  const int l = t & 63;
  const int w = t >> 6;
  const int wr = w >> 1, wc = w & 1;
  const int brow = blockIdx.x * 128;
  const int bcol = blockIdx.y * 128;
  const int l15 = l & 15, l4 = l >> 4;

  const int srow = t >> 2;
  const int scol = (t & 3) * 8;
  const float* ga = Ap + (size_t)(brow + srow) * K + scol;
  const unsigned short* gb = Bp + (size_t)(bcol + srow) * K + scol;

  f32x4 acc[4][4] = {};
  const int nk = K >> 5;

  float4 fa[4];
  // prologue: tile 0
  {
    fa[0] = *(const float4*)ga;
    fa[1] = *(const float4*)(ga + 4);
    fa[2] = *(const float4*)(ga + (size_t)64 * K);
    fa[3] = *(const float4*)(ga + (size_t)64 * K + 4);
    unsigned short* lb = lds_b[0] + w * 512;
    gload16(gb, lb);
    gload16(gb + (size_t)64 * K, lb + 2048);
    uint4 u0, u1;
    u0.x = cvtpk(fa[0].x, fa[0].y); u0.y = cvtpk(fa[0].z, fa[0].w);
    u0.z = cvtpk(fa[1].x, fa[1].y); u0.w = cvtpk(fa[1].z, fa[1].w);
    u1.x = cvtpk(fa[2].x, fa[2].y); u1.y = cvtpk(fa[2].z, fa[2].w);
    u1.z = cvtpk(fa[3].x, fa[3].y); u1.w = cvtpk(fa[3].z, fa[3].w);
    *(uint4*)&lds_a[0][srow * 32 + scol] = u0;
    *(uint4*)&lds_a[0][(srow + 64) * 32 + scol] = u1;
  }
  __syncthreads();

  int buf = 0;
  for (int kt = 0; kt < nk; ++kt) {
    const bool more = kt + 1 < nk;
    if (more) {                            // issue next-tile loads early
      const size_t ko = (size_t)(kt + 1) * 32;
      fa[0] = *(const float4*)(ga + ko);
      fa[1] = *(const float4*)(ga + ko + 4);
      fa[2] = *(const float4*)(ga + ko + (size_t)64 * K);
      fa[3] = *(const float4*)(ga + ko + (size_t)64 * K + 4);
      unsigned short* lb = lds_b[buf ^ 1] + w * 512;
      gload16(gb + ko, lb);
      gload16(gb + ko + (size_t)64 * K, lb + 2048);
    }
    bf16x8 af[4], bfr[4];
#pragma unroll
    for (int i = 0; i < 4; ++i) {
      af[i]  = *(const bf16x8*)&lds_a[buf][(wr * 64 + i * 16 + l15) * 32 + l4 * 8];
      bfr[i] = *(const bf16x8*)&lds_b[buf][(wc * 64 + i * 16 + l15) * 32 + l4 * 8];
    }
#pragma unroll
    for (int i = 0; i < 4; ++i)
#pragma unroll
      for (int j = 0; j < 4; ++j)
        acc[i][j] = __builtin_amdgcn_mfma_f32_16x16x32_bf16(af[i], bfr[j], acc[i][j], 0, 0, 0);
    if (more) {                            // T14 late-write A (hidden under MFMA)
      uint4 u0, u1;
      u0.x = cvtpk(fa[0].x, fa[0].y); u0.y = cvtpk(fa[0].z, fa[0].w);
      u0.z = cvtpk(fa[1].x, fa[1].y); u0.w = cvtpk(fa[1].z, fa[1].w);
      u1.x = cvtpk(fa[2].x, fa[2].y); u1.y = cvtpk(fa[2].z, fa[2].w);
      u1.z = cvtpk(fa[3].x, fa[3].y); u1.w = cvtpk(fa[3].z, fa[3].w);
      *(uint4*)&lds_a[buf ^ 1][srow * 32 + scol] = u0;
      *(uint4*)&lds_a[buf ^ 1][(srow + 64) * 32 + scol] = u1;
    }
    __syncthreads();
    buf ^= 1;
  }

#pragma unroll
  for (int i = 0; i < 4; ++i)
#pragma unroll
    for (int j = 0; j < 4; ++j)
#pragma unroll
      for (int r = 0; r < 4; ++r) {
        const int row = brow + wr * 64 + i * 16 + l4 * 4 + r;
        const int col = bcol + wc * 64 + j * 16 + l15;
        Cp[(size_t)row * N + col] = f2bf(acc[i][j][r]);
      }
}

// ---------------------------------------------------------------------------
// gemm2: C[M,N] = A[M,K] @ B[N,K]^T + bias, all-bf16 inputs via gload_lds,
// C f32. 64x128 tile (384 blocks at M=4096,N=768), BK=32, 2-phase dbuf.
__global__ __launch_bounds__(256)
void gemm2_kernel(const unsigned short* __restrict__ Ap,
                  const unsigned short* __restrict__ Bp,
                  const float* __restrict__ bias, float* __restrict__ Cp,
                  int M, int N, int K) {
  __shared__ __align__(16) unsigned short lds_a[2][64 * 32];
  __shared__ __align__(16) unsigned short lds_b[2][128 * 32];
  const int t = threadIdx.x;
  const int l = t & 63;
  const int w = t >> 6;
  const int wr = w >> 1, wc = w & 1;          // wave: rows wr*32, cols wc*64
  const int brow = blockIdx.x * 64;
  const int bcol = blockIdx.y * 128;
  const int l15 = l & 15, l4 = l >> 4;

  const int srow = t >> 2;
  const int scol = (t & 3) * 8;
  const unsigned short* ga = Ap + (size_t)(brow + srow) * K + scol;
  const unsigned short* gb = Bp + (size_t)(bcol + srow) * K + scol;

  f32x4 acc[2][4] = {};
  const int nk = K >> 5;

  {
    gload16(ga, lds_a[0] + w * 512);
    unsigned short* lb = lds_b[0] + w * 512;
    gload16(gb, lb);
    gload16(gb + (size_t)64 * K, lb + 2048);
  }
  __syncthreads();

  int buf = 0;
  for (int kt = 0; kt < nk; ++kt) {
    if (kt + 1 < nk) {
      const size_t ko = (size_t)(kt + 1) * 32;
      gload16(ga + ko, lds_a[buf ^ 1] + w * 512);
      unsigned short* lb = lds_b[buf ^ 1] + w * 512;
      gload16(gb + ko, lb);
      gload16(gb + ko + (size_t)64 * K, lb + 2048);
    }
    bf16x8 af[2], bfr[4];
#pragma unroll
    for (int i = 0; i < 2; ++i)
      af[i] = *(const bf16x8*)&lds_a[buf][(wr * 32 + i * 16 + l15) * 32 + l4 * 8];
#pragma unroll
    for (int j = 0; j < 4; ++j)
      bfr[j] = *(const bf16x8*)&lds_b[buf][(wc * 64 + j * 16 + l15) * 32 + l4 * 8];
#pragma unroll
    for (int i = 0; i < 2; ++i)
#pragma unroll
      for (int j = 0; j < 4; ++j)
        acc[i][j] = __builtin_amdgcn_mfma_f32_16x16x32_bf16(af[i], bfr[j], acc[i][j], 0, 0, 0);
    __syncthreads();
    buf ^= 1;
  }

#pragma unroll
  for (int i = 0; i < 2; ++i)
#pragma unroll
    for (int j = 0; j < 4; ++j)
#pragma unroll
      for (int r = 0; r < 4; ++r) {
        const int row = brow + wr * 32 + i * 16 + l4 * 4 + r;
        const int col = bcol + wc * 64 + j * 16 + l15;
        Cp[(size_t)row * N + col] = acc[i][j][r] + bias[col];
      }
}

// ---------------------------------------------------------------------------
// Flash attention, 32x32x16 MFMA, swapped QK^T, no max-tracking, ones-MFMA psum.
// grid = (B*H, N/256); 512 thr = 8 waves; wave w owns q [q0+32w, q0+32w+32).
// KV tiles of 64, double-buffered, T14 reg-staging, 1 barrier/iter. Staging
// spread over 512 threads (1 b128 K + 1 b128 V + 8 scalar V-writes each).
__global__ __launch_bounds__(512)
void attn_kernel(const unsigned short* __restrict__ qkv,
                 const float* __restrict__ elev,
                 const float* __restrict__ alpha_p,
                 unsigned short* __restrict__ aout) {
  __shared__ __align__(16) unsigned short lds_k[2][64 * 64];
  __shared__ __align__(16) unsigned short lds_vt[2][64 * 64];   // [d][kv], swizzled
  __shared__ __align__(16) float lds_ej[2][64];

  const int t = threadIdx.x;
  const int l = t & 63;
  const int w = t >> 6;                    // 0..7
  const int l31 = l & 31;
  const int h = l >> 5;
  const int b = blockIdx.x / 12, hd = blockIdx.x % 12;
  const int q0 = blockIdx.y * 256 + w * 32;

  const float cE = fmaxf(alpha_p[0], 0.f) * (1.4426950408889634f * 1e-3f);
  const float c1 = 0.18033688011112042f;   // 0.125 * log2(e)

  const size_t rs = 2304;
  const unsigned short* qbase = qkv + ((size_t)b * 2048) * rs + hd * 64;
  const unsigned short* kbase = qbase + 768;
  const unsigned short* vbase = qbase + 1536;

  bf16x8 qa[4];
  {
    const unsigned short* qp = qbase + (size_t)(q0 + l31) * rs + h * 8;
#pragma unroll
    for (int ks = 0; ks < 4; ++ks) qa[ks] = *(const bf16x8*)(qp + ks * 16);
  }
  const float eiv = elev[(size_t)b * 2048 + q0 + l31] * cE;

  // all-ones bf16 B operand for psum MFMA
  uint4 onesu; onesu.x = onesu.y = onesu.z = onesu.w = 0x3F803F80u;
  const bf16x8 onesf = __builtin_bit_cast(bf16x8, onesu);

  f32x16 o[2] = {};
  f32x16 ps = {};

  // staging: 512 threads cover the 64x64 K and V tiles once each
  const int sr = t >> 3;          // row 0..63
  const int sc = (t & 7) * 8;     // col

  uint4 rk, rv;
  float evn = 0.f;

  // prologue: stage tile 0
  rk = *(const uint4*)(kbase + (size_t)sr * rs + sc);
  rv = *(const uint4*)(vbase + (size_t)sr * rs + sc);
  if (t < 64) evn = elev[(size_t)b * 2048 + t];
  *(uint4*)&lds_k[0][sr * 64 + (sc ^ sw8(sr))] = rk;
  {
    union { uint4 u; unsigned short s[8]; } vu; vu.u = rv;
#pragma unroll
    for (int j = 0; j < 8; ++j) {
      const int d = sc + j;
      lds_vt[0][d * 64 + (sr ^ sw8(d))] = vu.s[j];
    }
  }
  if (t < 64) lds_ej[0][t] = evn * cE;
  __syncthreads();

  for (int it = 0; it < 32; ++it) {
    const int cur = it & 1;
    const bool more = it < 31;
    if (more) {
      const int kv1 = (it + 1) * 64;
      rk = *(const uint4*)(kbase + (size_t)(kv1 + sr) * rs + sc);
      rv = *(const uint4*)(vbase + (size_t)(kv1 + sr) * rs + sc);
      if (t < 64) evn = elev[(size_t)b * 2048 + kv1 + t];
    }

    // --- S^T = K x Q ---
    f32x16 st[2] = {};
    __builtin_amdgcn_s_setprio(1);
#pragma unroll
    for (int kst = 0; kst < 4; ++kst) {
      const int col = kst * 16 + h * 8;
#pragma unroll
      for (int mb = 0; mb < 2; ++mb) {
        const int row = mb * 32 + l31;
        bf16x8 kf = *(const bf16x8*)&lds_k[cur][row * 64 + (col ^ sw8(row))];
        st[mb] = __builtin_amdgcn_mfma_f32_32x32x16_bf16(kf, qa[kst], st[mb], 0, 0, 0);
      }
    }
    __builtin_amdgcn_s_setprio(0);

    // --- softmax (no max-tracking) + in-register P pack ---
    bf16x8 pa[4];
#pragma unroll
    for (int mb = 0; mb < 2; ++mb) {
      float p16[16];
#pragma unroll
      for (int rr = 0; rr < 4; ++rr) {
        const float4 ejq = *(const float4*)&lds_ej[cur][mb * 32 + rr * 8 + h * 4];
#pragma unroll
        for (int jl = 0; jl < 4; ++jl) {
          const int r = rr * 4 + jl;
          const float bm = __builtin_amdgcn_fmed3f(ejq[jl] - eiv, 0.f, 14.4269504f);
          p16[r] = exp2v(__builtin_fmaf(st[mb][r], c1, -bm));
        }
      }
#pragma unroll
      for (int ks2 = 0; ks2 < 2; ++ks2) {
        unsigned u0 = cvtpk(p16[ks2 * 8 + 0], p16[ks2 * 8 + 1]);
        unsigned u1 = cvtpk(p16[ks2 * 8 + 2], p16[ks2 * 8 + 3]);
        unsigned v0 = cvtpk(p16[ks2 * 8 + 4], p16[ks2 * 8 + 5]);
        unsigned v1 = cvtpk(p16[ks2 * 8 + 6], p16[ks2 * 8 + 7]);
        asm volatile("v_permlane32_swap_b32 %0, %1" : "+v"(u0), "+v"(v0));
        asm volatile("v_permlane32_swap_b32 %0, %1" : "+v"(u1), "+v"(v1));
        uint4 fr; fr.x = u0; fr.y = u1; fr.z = v0; fr.w = v1;
        pa[mb * 2 + ks2] = __builtin_bit_cast(bf16x8, fr);
      }
    }

    // --- O += P @ V ; psum via ones-MFMA (same row mapping as O) ---
    __builtin_amdgcn_s_setprio(1);
#pragma unroll
    for (int ks = 0; ks < 4; ++ks) {
      const int col = ks * 16 + h * 8;
#pragma unroll
      for (int nb = 0; nb < 2; ++nb) {
        const int row = nb * 32 + l31;
        bf16x8 vf = *(const bf16x8*)&lds_vt[cur][row * 64 + (col ^ sw8(row))];
        o[nb] = __builtin_amdgcn_mfma_f32_32x32x16_bf16(pa[ks], vf, o[nb], 0, 0, 0);
      }
      ps = __builtin_amdgcn_mfma_f32_32x32x16_bf16(pa[ks], onesf, ps, 0, 0, 0);
    }
    __builtin_amdgcn_s_setprio(0);

    // --- T14 late-write next tile ---
    if (more) {
      const int nxt = cur ^ 1;
      *(uint4*)&lds_k[nxt][sr * 64 + (sc ^ sw8(sr))] = rk;
      union { uint4 u; unsigned short s[8]; } vu; vu.u = rv;
#pragma unroll
      for (int j = 0; j < 8; ++j) {
        const int d = sc + j;
        lds_vt[nxt][d * 64 + (sr ^ sw8(d))] = vu.s[j];
      }
      if (t < 64) lds_ej[nxt][t] = evn * cE;
    }
    __syncthreads();
  }

  // --- epilogue: purely per-lane normalize (ps rows == o rows), store bf16 ---
  float inv[16];
#pragma unroll
  for (int r = 0; r < 16; ++r) inv[r] = 1.0f / ps[r];
#pragma unroll
  for (int nb = 0; nb < 2; ++nb) {
    const int col = hd * 64 + nb * 32 + l31;
#pragma unroll
    for (int rr = 0; rr < 4; ++rr)
#pragma unroll
      for (int jl = 0; jl < 4; ++jl) {
        const int r = rr * 4 + jl;
        const int q = q0 + rr * 8 + h * 4 + jl;
        aout[((size_t)b * 2048 + q) * 768 + col] = f2bf(o[nb][r] * inv[r]);
      }
  }
}

extern "C" void kernel_launch(void* const* d_in, const int* in_sizes, int n_in,
                              void* d_out, int out_size, void* d_ws, size_t ws_size,
                              hipStream_t stream) {
  const float* x      = (const float*)d_in[0];   // [2,2048,768]
  const float* elev   = (const float*)d_in[1];   // [2,2048]
  const float* w_qkv  = (const float*)d_in[2];   // [2304,768]
  const float* w_proj = (const float*)d_in[3];   // [768,768]
  const float* b_proj = (const float*)d_in[4];   // [768]
  const float* alpha  = (const float*)d_in[5];   // [1]
  float* out = (float*)d_out;                    // [2,2048,768] f32

  // ws layout (bf16): qkvb [4096,2304] ; aob [4096,768] ; wqkvb [2304,768] ;
  // wprojb [768,768]  => 29.9 MB total
  unsigned short* qkvb   = (unsigned short*)d_ws;
  unsigned short* aob    = qkvb + (size_t)4096 * 2304;
  unsigned short* wqkvb  = aob + (size_t)4096 * 768;
  unsigned short* wprojb = wqkvb + (size_t)2304 * 768;

  // convert the two weight matrices (x is converted inside gemm1 staging)
  cvt2_kernel<<<1152, 256, 0, stream>>>(w_qkv, wqkvb, 2304 * 768 / 8,
                                        w_proj, wprojb, 768 * 768 / 8);

  // 1) qkv = x @ w_qkv^T   (A = f32 x, converted in-register)
  gemm_a32_kernel<<<dim3(32, 18), 256, 0, stream>>>(
      x, wqkvb, qkvb, 4096, 2304, 768);

  // 2) flash attention with elevation bias -> normalized bf16 aob
  attn_kernel<<<dim3(24, 8), 512, 0, stream>>>(qkvb, elev, alpha, aob);

  // 3) out = aob @ w_proj^T + b_proj
  gemm2_kernel<<<dim3(64, 6), 256, 0, stream>>>(
      aob, wprojb, b_proj, out, 4096, 768, 768);
}

// Round 12
// 100.219 us; speedup vs baseline: 1.6792x; 1.0024x over previous
//
#include <hip/hip_runtime.h>

// PhysicsGuidedAttention: B=2, N=2048, D=768, H=12, Hd=64
// qkv = x @ w_qkv.T ; flash-attn with elevation bias ; out = attn_out @ w_proj.T + b_proj
// R12: attn = R11 (8-wave/256-q, dbuf, ones-MFMA psum) with main loop
//      macro-unrolled x2 (literal buffer indices -> all LDS addresses hoisted).
//      gemm1 = R11 + XCD-ownership block remap (A row-slice stays in own L2).
//      gemm2 64-row tiles; cvt2 weights only.

typedef __attribute__((ext_vector_type(8))) short bf16x8;   // 8 bf16 = 4 VGPRs
typedef __attribute__((ext_vector_type(4))) float f32x4;
typedef __attribute__((ext_vector_type(16))) float f32x16;  // 32x32 accumulator

__device__ __forceinline__ unsigned short f2bf(float f) {
  unsigned int u = __builtin_bit_cast(unsigned int, f);
  u += 0x7fffu + ((u >> 16) & 1u);        // round-to-nearest-even
  return (unsigned short)(u >> 16);
}

__device__ __forceinline__ unsigned cvtpk(float lo, float hi) {
  unsigned r;
  asm("v_cvt_pk_bf16_f32 %0, %1, %2" : "=v"(r) : "v"(lo), "v"(hi));
  return r;
}

__device__ __forceinline__ float exp2v(float x) {
  float r;
  asm("v_exp_f32 %0, %1" : "=v"(r) : "v"(x));
  return r;
}

// XOR swizzle on element index: spreads 128B-stride row slots across banks.
__device__ __forceinline__ int sw8(int row) {
  return ((row ^ (row >> 3)) & 7) << 3;
}

__device__ __forceinline__ void gload16(const unsigned short* g, unsigned short* l) {
  __builtin_amdgcn_global_load_lds(
      (const __attribute__((address_space(1))) unsigned int*)g,
      (__attribute__((address_space(3))) unsigned int*)l, 16, 0, 0);
}

// ---------------------------------------------------------------------------
// f32 -> bf16 converts for w_qkv and w_proj in one launch.
__global__ __launch_bounds__(256)
void cvt2_kernel(const float* __restrict__ a, unsigned short* __restrict__ ao, int na8,
                 const float* __restrict__ b, unsigned short* __restrict__ bo, int nb8) {
  int i = blockIdx.x * 256 + threadIdx.x;
  const float* src; unsigned short* dst;
  if (i < na8) { src = a; dst = ao; }
  else {
    i -= na8;
    if (i >= nb8) return;
    src = b; dst = bo;
  }
  const float4 f0 = ((const float4*)src)[i * 2];
  const float4 f1 = ((const float4*)src)[i * 2 + 1];
  uint4 v;
  v.x = cvtpk(f0.x, f0.y);
  v.y = cvtpk(f0.z, f0.w);
  v.z = cvtpk(f1.x, f1.y);
  v.w = cvtpk(f1.z, f1.w);
  ((uint4*)dst)[i] = v;
}

// ---------------------------------------------------------------------------
// gemm1: C[M,N] = A[M,K] @ B[N,K]^T with A = f32 (converted in staging regs),
// B bf16 via gload_lds, C bf16. 128x128 tile, BK=32, 2-phase dbuf (T14 for A).
// XCD-ownership remap: bid%8 = XCD; each XCD owns 4 row-tiles x 18 col-tiles
// so its 1.6 MB f32 A-slice stays resident in its own L2 across the col sweep.
__global__ __launch_bounds__(256)
void gemm_a32_kernel(const float* __restrict__ Ap,
                     const unsigned short* __restrict__ Bp,
                     unsigned short* __restrict__ Cp, int M, int N, int K) {
  __shared__ __align__(16) unsigned short lds_a[2][128 * 32];
  __shared__ __align__(16) unsigned short lds_b[2][128 * 32];
  const int t = threadIdx.x;
  const int l = t & 63;
  const int w = t >> 6;
  const int wr = w >> 1, wc = w & 1;
  const int bid = blockIdx.x + gridDim.x * blockIdx.y;   // linear dispatch order
  const int xcd = bid & 7;
  const int idx = bid >> 3;                              // 0..71
  const int brow = (xcd * 4 + (idx & 3)) * 128;
  const int bcol = (idx >> 2) * 128;
  const int l15 = l & 15, l4 = l >> 4;

  const int srow = t >> 2;
  const int scol = (t & 3) * 8;
  const float* ga = Ap + (size_t)(brow + srow) * K + scol;
  const unsigned short* gb = Bp + (size_t)(bcol + srow) * K + scol;

  f32x4 acc[4][4] = {};
  const int nk = K >> 5;

  float4 fa[4];
  // prologue: tile 0
  {
    fa[0] = *(const float4*)ga;
    fa[1] = *(const float4*)(ga + 4);
    fa[2] = *(const float4*)(ga + (size_t)64 * K);
    fa[3] = *(const float4*)(ga + (size_t)64 * K + 4);
    unsigned short* lb = lds_b[0] + w * 512;
    gload16(gb, lb);
    gload16(gb + (size_t)64 * K, lb + 2048);
    uint4 u0, u1;
    u0.x = cvtpk(fa[0].x, fa[0].y); u0.y = cvtpk(fa[0].z, fa[0].w);
    u0.z = cvtpk(fa[1].x, fa[1].y); u0.w = cvtpk(fa[1].z, fa[1].w);
    u1.x = cvtpk(fa[2].x, fa[2].y); u1.y = cvtpk(fa[2].z, fa[2].w);
    u1.z = cvtpk(fa[3].x, fa[3].y); u1.w = cvtpk(fa[3].z, fa[3].w);
    *(uint4*)&lds_a[0][srow * 32 + scol] = u0;
    *(uint4*)&lds_a[0][(srow + 64) * 32 + scol] = u1;
  }
  __syncthreads();

  int buf = 0;
  for (int kt = 0; kt < nk; ++kt) {
    const bool more = kt + 1 < nk;
    if (more) {                            // issue next-tile loads early
      const size_t ko = (size_t)(kt + 1) * 32;
      fa[0] = *(const float4*)(ga + ko);
      fa[1] = *(const float4*)(ga + ko + 4);
      fa[2] = *(const float4*)(ga + ko + (size_t)64 * K);
      fa[3] = *(const float4*)(ga + ko + (size_t)64 * K + 4);
      unsigned short* lb = lds_b[buf ^ 1] + w * 512;
      gload16(gb + ko, lb);
      gload16(gb + ko + (size_t)64 * K, lb + 2048);
    }
    bf16x8 af[4], bfr[4];
#pragma unroll
    for (int i = 0; i < 4; ++i) {
      af[i]  = *(const bf16x8*)&lds_a[buf][(wr * 64 + i * 16 + l15) * 32 + l4 * 8];
      bfr[i] = *(const bf16x8*)&lds_b[buf][(wc * 64 + i * 16 + l15) * 32 + l4 * 8];
    }
#pragma unroll
    for (int i = 0; i < 4; ++i)
#pragma unroll
      for (int j = 0; j < 4; ++j)
        acc[i][j] = __builtin_amdgcn_mfma_f32_16x16x32_bf16(af[i], bfr[j], acc[i][j], 0, 0, 0);
    if (more) {                            // T14 late-write A (hidden under MFMA)
      uint4 u0, u1;
      u0.x = cvtpk(fa[0].x, fa[0].y); u0.y = cvtpk(fa[0].z, fa[0].w);
      u0.z = cvtpk(fa[1].x, fa[1].y); u0.w = cvtpk(fa[1].z, fa[1].w);
      u1.x = cvtpk(fa[2].x, fa[2].y); u1.y = cvtpk(fa[2].z, fa[2].w);
      u1.z = cvtpk(fa[3].x, fa[3].y); u1.w = cvtpk(fa[3].z, fa[3].w);
      *(uint4*)&lds_a[buf ^ 1][srow * 32 + scol] = u0;
      *(uint4*)&lds_a[buf ^ 1][(srow + 64) * 32 + scol] = u1;
    }
    __syncthreads();
    buf ^= 1;
  }

#pragma unroll
  for (int i = 0; i < 4; ++i)
#pragma unroll
    for (int j = 0; j < 4; ++j)
#pragma unroll
      for (int r = 0; r < 4; ++r) {
        const int row = brow + wr * 64 + i * 16 + l4 * 4 + r;
        const int col = bcol + wc * 64 + j * 16 + l15;
        Cp[(size_t)row * N + col] = f2bf(acc[i][j][r]);
      }
}

// ---------------------------------------------------------------------------
// gemm2: C[M,N] = A[M,K] @ B[N,K]^T + bias, all-bf16 inputs via gload_lds,
// C f32. 64x128 tile (384 blocks at M=4096,N=768), BK=32, 2-phase dbuf.
__global__ __launch_bounds__(256)
void gemm2_kernel(const unsigned short* __restrict__ Ap,
                  const unsigned short* __restrict__ Bp,
                  const float* __restrict__ bias, float* __restrict__ Cp,
                  int M, int N, int K) {
  __shared__ __align__(16) unsigned short lds_a[2][64 * 32];
  __shared__ __align__(16) unsigned short lds_b[2][128 * 32];
  const int t = threadIdx.x;
  const int l = t & 63;
  const int w = t >> 6;
  const int wr = w >> 1, wc = w & 1;          // wave: rows wr*32, cols wc*64
  const int brow = blockIdx.x * 64;
  const int bcol = blockIdx.y * 128;
  const int l15 = l & 15, l4 = l >> 4;

  const int srow = t >> 2;
  const int scol = (t & 3) * 8;
  const unsigned short* ga = Ap + (size_t)(brow + srow) * K + scol;
  const unsigned short* gb = Bp + (size_t)(bcol + srow) * K + scol;

  f32x4 acc[2][4] = {};
  const int nk = K >> 5;

  {
    gload16(ga, lds_a[0] + w * 512);
    unsigned short* lb = lds_b[0] + w * 512;
    gload16(gb, lb);
    gload16(gb + (size_t)64 * K, lb + 2048);
  }
  __syncthreads();

  int buf = 0;
  for (int kt = 0; kt < nk; ++kt) {
    if (kt + 1 < nk) {
      const size_t ko = (size_t)(kt + 1) * 32;
      gload16(ga + ko, lds_a[buf ^ 1] + w * 512);
      unsigned short* lb = lds_b[buf ^ 1] + w * 512;
      gload16(gb + ko, lb);
      gload16(gb + ko + (size_t)64 * K, lb + 2048);
    }
    bf16x8 af[2], bfr[4];
#pragma unroll
    for (int i = 0; i < 2; ++i)
      af[i] = *(const bf16x8*)&lds_a[buf][(wr * 32 + i * 16 + l15) * 32 + l4 * 8];
#pragma unroll
    for (int j = 0; j < 4; ++j)
      bfr[j] = *(const bf16x8*)&lds_b[buf][(wc * 64 + j * 16 + l15) * 32 + l4 * 8];
#pragma unroll
    for (int i = 0; i < 2; ++i)
#pragma unroll
      for (int j = 0; j < 4; ++j)
        acc[i][j] = __builtin_amdgcn_mfma_f32_16x16x32_bf16(af[i], bfr[j], acc[i][j], 0, 0, 0);
    __syncthreads();
    buf ^= 1;
  }

#pragma unroll
  for (int i = 0; i < 2; ++i)
#pragma unroll
    for (int j = 0; j < 4; ++j)
#pragma unroll
      for (int r = 0; r < 4; ++r) {
        const int row = brow + wr * 32 + i * 16 + l4 * 4 + r;
        const int col = bcol + wc * 64 + j * 16 + l15;
        Cp[(size_t)row * N + col] = acc[i][j][r] + bias[col];
      }
}

// ---------------------------------------------------------------------------
// Flash attention, 32x32x16 MFMA, swapped QK^T, no max-tracking, ones-MFMA psum.
// grid = (B*H, N/256); 512 thr = 8 waves; wave w owns q [q0+32w, q0+32w+32).
// Main loop unrolled x2 with LITERAL buffer indices: all swizzled LDS addresses
// are lane-constant -> hoisted out of the loop by the compiler.
__global__ __launch_bounds__(512)
void attn_kernel(const unsigned short* __restrict__ qkv,
                 const float* __restrict__ elev,
                 const float* __restrict__ alpha_p,
                 unsigned short* __restrict__ aout) {
  __shared__ __align__(16) unsigned short lds_k[2][64 * 64];
  __shared__ __align__(16) unsigned short lds_vt[2][64 * 64];   // [d][kv], swizzled
  __shared__ __align__(16) float lds_ej[2][64];

  const int t = threadIdx.x;
  const int l = t & 63;
  const int w = t >> 6;                    // 0..7
  const int l31 = l & 31;
  const int h = l >> 5;
  const int b = blockIdx.x / 12, hd = blockIdx.x % 12;
  const int q0 = blockIdx.y * 256 + w * 32;

  const float cE = fmaxf(alpha_p[0], 0.f) * (1.4426950408889634f * 1e-3f);
  const float c1 = 0.18033688011112042f;   // 0.125 * log2(e)

  const size_t rs = 2304;
  const unsigned short* qbase = qkv + ((size_t)b * 2048) * rs + hd * 64;
  const unsigned short* kbase = qbase + 768;
  const unsigned short* vbase = qbase + 1536;

  bf16x8 qa[4];
  {
    const unsigned short* qp = qbase + (size_t)(q0 + l31) * rs + h * 8;
#pragma unroll
    for (int ks = 0; ks < 4; ++ks) qa[ks] = *(const bf16x8*)(qp + ks * 16);
  }
  const float eiv = elev[(size_t)b * 2048 + q0 + l31] * cE;

  // all-ones bf16 B operand for psum MFMA
  uint4 onesu; onesu.x = onesu.y = onesu.z = onesu.w = 0x3F803F80u;
  const bf16x8 onesf = __builtin_bit_cast(bf16x8, onesu);

  f32x16 o[2] = {};
  f32x16 ps = {};

  // staging: 512 threads cover the 64x64 K and V tiles once each
  const int sr = t >> 3;          // row 0..63
  const int sc = (t & 7) * 8;     // col

  uint4 rk, rv;
  float evn = 0.f;

  // prologue: stage tile 0 into buf 0
  rk = *(const uint4*)(kbase + (size_t)sr * rs + sc);
  rv = *(const uint4*)(vbase + (size_t)sr * rs + sc);
  if (t < 64) evn = elev[(size_t)b * 2048 + t];
  *(uint4*)&lds_k[0][sr * 64 + (sc ^ sw8(sr))] = rk;
  {
    union { uint4 u; unsigned short s[8]; } vu; vu.u = rv;
#pragma unroll
    for (int j = 0; j < 8; ++j) {
      const int d = sc + j;
      lds_vt[0][d * 64 + (sr ^ sw8(d))] = vu.s[j];
    }
  }
  if (t < 64) lds_ej[0][t] = evn * cE;
  __syncthreads();

  // One iteration with compile-time buffer index CUR. Prefetches tile IT+1
  // into registers early (when PRE), computes on buf CUR, late-writes buf 1-CUR.
#define ATTN_STEP(IT, CUR, PRE)                                                \
  {                                                                            \
    if (PRE) {                                                                 \
      const int kv1 = ((IT) + 1) * 64;                                         \
      rk = *(const uint4*)(kbase + (size_t)(kv1 + sr) * rs + sc);              \
      rv = *(const uint4*)(vbase + (size_t)(kv1 + sr) * rs + sc);              \
      if (t < 64) evn = elev[(size_t)b * 2048 + kv1 + t];                      \
    }                                                                          \
    f32x16 st[2] = {};                                                         \
    __builtin_amdgcn_s_setprio(1);                                             \
    _Pragma("unroll")                                                          \
    for (int kst = 0; kst < 4; ++kst) {                                        \
      const int col = kst * 16 + h * 8;                                        \
      _Pragma("unroll")                                                        \
      for (int mb = 0; mb < 2; ++mb) {                                         \
        const int row = mb * 32 + l31;                                         \
        bf16x8 kf = *(const bf16x8*)&lds_k[CUR][row * 64 + (col ^ sw8(row))];  \
        st[mb] = __builtin_amdgcn_mfma_f32_32x32x16_bf16(kf, qa[kst], st[mb], 0, 0, 0); \
      }                                                                        \
    }                                                                          \
    __builtin_amdgcn_s_setprio(0);                                             \
    bf16x8 pa[4];                                                              \
    _Pragma("unroll")                                                          \
    for (int mb = 0; mb < 2; ++mb) {                                           \
      float p16[16];                                                           \
      _Pragma("unroll")                                                        \
      for (int rr = 0; rr < 4; ++rr) {                                         \
        const float4 ejq = *(const float4*)&lds_ej[CUR][mb * 32 + rr * 8 + h * 4]; \
        _Pragma("unroll")                                                      \
        for (int jl = 0; jl < 4; ++jl) {                                       \
          const int r = rr * 4 + jl;                                           \
          const float bm = __builtin_amdgcn_fmed3f(ejq[jl] - eiv, 0.f, 14.4269504f); \
          p16[r] = exp2v(__builtin_fmaf(st[mb][r], c1, -bm));                  \
        }                                                                      \
      }                                                                        \
      _Pragma("unroll")                                                        \
      for (int ks2 = 0; ks2 < 2; ++ks2) {                                      \
        unsigned u0 = cvtpk(p16[ks2 * 8 + 0], p16[ks2 * 8 + 1]);               \
        unsigned u1 = cvtpk(p16[ks2 * 8 + 2], p16[ks2 * 8 + 3]);               \
        unsigned v0 = cvtpk(p16[ks2 * 8 + 4], p16[ks2 * 8 + 5]);               \
        unsigned v1 = cvtpk(p16[ks2 * 8 + 6], p16[ks2 * 8 + 7]);               \
        asm volatile("v_permlane32_swap_b32 %0, %1" : "+v"(u0), "+v"(v0));     \
        asm volatile("v_permlane32_swap_b32 %0, %1" : "+v"(u1), "+v"(v1));     \
        uint4 fr; fr.x = u0; fr.y = u1; fr.z = v0; fr.w = v1;                  \
        pa[mb * 2 + ks2] = __builtin_bit_cast(bf16x8, fr);                     \
      }                                                                        \
    }                                                                          \
    __builtin_amdgcn_s_setprio(1);                                             \
    _Pragma("unroll")                                                          \
    for (int ks = 0; ks < 4; ++ks) {                                           \
      const int col = ks * 16 + h * 8;                                         \
      _Pragma("unroll")                                                        \
      for (int nb = 0; nb < 2; ++nb) {                                         \
        const int row = nb * 32 + l31;                                         \
        bf16x8 vf = *(const bf16x8*)&lds_vt[CUR][row * 64 + (col ^ sw8(row))]; \
        o[nb] = __builtin_amdgcn_mfma_f32_32x32x16_bf16(pa[ks], vf, o[nb], 0, 0, 0); \
      }                                                                        \
      ps = __builtin_amdgcn_mfma_f32_32x32x16_bf16(pa[ks], onesf, ps, 0, 0, 0); \
    }                                                                          \
    __builtin_amdgcn_s_setprio(0);                                             \
    if (PRE) {                                                                 \
      *(uint4*)&lds_k[1 - (CUR)][sr * 64 + (sc ^ sw8(sr))] = rk;               \
      union { uint4 u; unsigned short s[8]; } vu; vu.u = rv;                   \
      _Pragma("unroll")                                                        \
      for (int j = 0; j < 8; ++j) {                                            \
        const int d = sc + j;                                                  \
        lds_vt[1 - (CUR)][d * 64 + (sr ^ sw8(d))] = vu.s[j];                   \
      }                                                                        \
      if (t < 64) lds_ej[1 - (CUR)][t] = evn * cE;                             \
    }                                                                          \
    __syncthreads();                                                           \
  }

  for (int s = 0; s < 16; ++s) {
    ATTN_STEP(2 * s, 0, true);
    ATTN_STEP(2 * s + 1, 1, s < 15);
  }
#undef ATTN_STEP

  // --- epilogue: purely per-lane normalize (ps rows == o rows), store bf16 ---
  float inv[16];
#pragma unroll
  for (int r = 0; r < 16; ++r) inv[r] = 1.0f / ps[r];
#pragma unroll
  for (int nb = 0; nb < 2; ++nb) {
    const int col = hd * 64 + nb * 32 + l31;
#pragma unroll
    for (int rr = 0; rr < 4; ++rr)
#pragma unroll
      for (int jl = 0; jl < 4; ++jl) {
        const int r = rr * 4 + jl;
        const int q = q0 + rr * 8 + h * 4 + jl;
        aout[((size_t)b * 2048 + q) * 768 + col] = f2bf(o[nb][r] * inv[r]);
      }
  }
}

extern "C" void kernel_launch(void* const* d_in, const int* in_sizes, int n_in,
                              void* d_out, int out_size, void* d_ws, size_t ws_size,
                              hipStream_t stream) {
  const float* x      = (const float*)d_in[0];   // [2,2048,768]
  const float* elev   = (const float*)d_in[1];   // [2,2048]
  const float* w_qkv  = (const float*)d_in[2];   // [2304,768]
  const float* w_proj = (const float*)d_in[3];   // [768,768]
  const float* b_proj = (const float*)d_in[4];   // [768]
  const float* alpha  = (const float*)d_in[5];   // [1]
  float* out = (float*)d_out;                    // [2,2048,768] f32

  // ws layout (bf16): qkvb [4096,2304] ; aob [4096,768] ; wqkvb [2304,768] ;
  // wprojb [768,768]  => 29.9 MB total
  unsigned short* qkvb   = (unsigned short*)d_ws;
  unsigned short* aob    = qkvb + (size_t)4096 * 2304;
  unsigned short* wqkvb  = aob + (size_t)4096 * 768;
  unsigned short* wprojb = wqkvb + (size_t)2304 * 768;

  // convert the two weight matrices (x is converted inside gemm1 staging)
  cvt2_kernel<<<1152, 256, 0, stream>>>(w_qkv, wqkvb, 2304 * 768 / 8,
                                        w_proj, wprojb, 768 * 768 / 8);

  // 1) qkv = x @ w_qkv^T   (A = f32 x, converted in-register)
  gemm_a32_kernel<<<dim3(32, 18), 256, 0, stream>>>(
      x, wqkvb, qkvb, 4096, 2304, 768);

  // 2) flash attention with elevation bias -> normalized bf16 aob
  attn_kernel<<<dim3(24, 8), 512, 0, stream>>>(qkvb, elev, alpha, aob);

  // 3) out = aob @ w_proj^T + b_proj
  gemm2_kernel<<<dim3(64, 6), 256, 0, stream>>>(
      aob, wprojb, b_proj, out, 4096, 768, 768);
}